// Round 1
// baseline (48944.080 us; speedup 1.0000x reference)
//
#include <hip/hip_runtime.h>

// Problem constants
#define BB 32
#define TT 1024
#define HH 1024

typedef float f32x4 __attribute__((ext_vector_type(4)));
typedef short bf16x8 __attribute__((ext_vector_type(8)));

__device__ __forceinline__ unsigned short f2bf(float f) {
  unsigned u = __builtin_bit_cast(unsigned, f);
  u += 0x7fffu + ((u >> 16) & 1u);   // RNE
  return (unsigned short)(u >> 16);
}
__device__ __forceinline__ float bf2f(unsigned short h) {
  return __builtin_bit_cast(float, (unsigned)h << 16);
}
__device__ __forceinline__ unsigned long long pk4(unsigned short a, unsigned short b,
                                                  unsigned short c, unsigned short d) {
  return (unsigned long long)a | ((unsigned long long)b << 16) |
         ((unsigned long long)c << 32) | ((unsigned long long)d << 48);
}
__device__ __forceinline__ void spinwait(const unsigned* p, unsigned tgt) {
  while (__hip_atomic_load(p, __ATOMIC_RELAXED, __HIP_MEMORY_SCOPE_AGENT) < tgt)
    __builtin_amdgcn_s_sleep(2);
}

// LDS: 3*33024 + 33280 + 4160 = 136,512 B  (fits 160 KiB, forces 1 WG/CU)
struct Shm {
  unsigned short whhi[16][1032];  // Wh rows n0..n0+15, hi bf16 (padded +8)
  unsigned short whlo[16][1032];  // Wh lo residual bf16
  unsigned short wx[16][1032];    // Wx rows, single bf16
  float abuf[16][520];            // fp32 A-stage: 16 rows x 512 K (padded +8)
  float red[4][260];              // cross-wave partial tiles
};

// Grid = 256 WGs x 256 thr, all co-resident (1/CU). WG 0..127: layer 1, 128..255: layer 2.
// Each WG: b-tile of 16 x j-tile of 16. Per step: pre = h_{t-1}@Wh^T (hi+lo passes)
//          + x_t@Wx^T (single pass) + bias; h_t = tanh(pre).
// h exchange fp32 via global: hbuf1 = [1025][32][1024] write-once slots (slot s = h_{s-1});
// hbuf2 = 2-slot ping-pong. flags[wg] = t+1 published after step t (release, agent scope).
__global__ __launch_bounds__(256) void rnn_fused(
    const float* __restrict__ x, const float* __restrict__ Wx,
    const float* __restrict__ Wh, const float* __restrict__ bx,
    const float* __restrict__ bh, float* __restrict__ out,
    float* __restrict__ hbuf1, float* __restrict__ hbuf2,
    unsigned* __restrict__ flags)
{
  __shared__ Shm s;
  const int tid   = threadIdx.x;
  const int wg    = blockIdx.x;
  const int layer = wg >> 7;            // 0 or 1
  const int lwg   = wg & 127;
  const int n0    = (lwg & 63) << 4;    // output-feature tile base
  const int b0    = (lwg >> 6) << 4;    // batch tile base
  const int lane  = tid & 63;
  const int wv    = tid >> 6;           // wave id (K-quarter)
  const int am    = lane & 15;          // MFMA A/B row/col lane index
  const int aq    = lane >> 4;          // MFMA quad

  // ---- preload weights into LDS (Wh hi/lo split, Wx single bf16) ----
  const float* WhL = Wh + layer * (HH * HH) + n0 * HH;
  const float* WxL = Wx + layer * (HH * HH) + n0 * HH;
  #pragma unroll 4
  for (int r = 0; r < 16; ++r) {
    int c   = (r << 8) + tid;           // 4096 chunks of 4 floats
    int row = c >> 8;
    int col = (c & 255) << 2;
    float4 w4 = *(const float4*)(WhL + row * HH + col);
    unsigned short h0 = f2bf(w4.x), h1 = f2bf(w4.y), h2 = f2bf(w4.z), h3 = f2bf(w4.w);
    *(unsigned long long*)(&s.whhi[row][col]) = pk4(h0, h1, h2, h3);
    *(unsigned long long*)(&s.whlo[row][col]) =
        pk4(f2bf(w4.x - bf2f(h0)), f2bf(w4.y - bf2f(h1)),
            f2bf(w4.z - bf2f(h2)), f2bf(w4.w - bf2f(h3)));
    float4 v4 = *(const float4*)(WxL + row * HH + col);
    *(unsigned long long*)(&s.wx[row][col]) =
        pk4(f2bf(v4.x), f2bf(v4.y), f2bf(v4.z), f2bf(v4.w));
  }

  // epilogue constants: thread tid owns element (row=tid>>4, col=tid&15) of the 16x16 tile
  const int   colE   = n0 + (tid & 15);
  const int   rowE   = tid >> 4;
  const float biasv  = bx[layer * HH + colE] + bh[layer * HH + colE];
  const int   off_bh = (b0 + rowE) * HH + colE;          // [b][j] offset
  const int   obase  = (b0 + rowE) * (TT * HH) + colE;   // d_out [b][t][j] base

  __syncthreads();

  for (int t = 0; t < TT; ++t) {
    // ---- wait for producers ----
    if (layer == 0) {
      if (tid < 128) spinwait(&flags[tid], (unsigned)t);                  // own layer
    } else {
      spinwait(&flags[tid], (unsigned)(tid < 128 ? t + 1 : t));           // l1 out + own
    }
    __syncthreads();
    __threadfence();  // acquire: invalidate stale cached lines before staging reads

    const float* hrd = layer ? (hbuf2 + (t & 1) * (BB * HH))
                             : (hbuf1 + t * (BB * HH));

    f32x4 accA = {0.f, 0.f, 0.f, 0.f};
    f32x4 accB = {0.f, 0.f, 0.f, 0.f};

    // 4 phases: p0/p1 = recurrent (K halves, Wh hi+lo), p2/p3 = input proj (Wx)
    for (int p = 0; p < 4; ++p) {
      const int kh = (p & 1) << 9;  // 0 or 512
      const float* sb;
      int stride;
      if (p < 2)           { sb = hrd + b0 * HH + kh;                          stride = HH; }
      else if (layer == 0) { sb = x + b0 * (TT * HH) + t * HH + kh;            stride = TT * HH; }
      else                 { sb = hbuf1 + (t + 1) * (BB * HH) + b0 * HH + kh;  stride = HH; }

      __syncthreads();
      #pragma unroll
      for (int r = 0; r < 8; ++r) {   // stage 16 rows x 512 fp32
        int c   = (r << 8) + tid;
        int row = c >> 7;
        int col = (c & 127) << 2;
        *(float4*)(&s.abuf[row][col]) = *(const float4*)(sb + row * stride + col);
      }
      __syncthreads();

      const int kq = wv << 7;         // this wave's 128-wide K slice of the 512
      #pragma unroll
      for (int ss = 0; ss < 4; ++ss) {
        const int kl = kq + (ss << 5) + (aq << 3);
        float4 a0 = *(const float4*)(&s.abuf[am][kl]);
        float4 a1 = *(const float4*)(&s.abuf[am][kl + 4]);
        bf16x8 af;
        af[0] = (short)f2bf(a0.x); af[1] = (short)f2bf(a0.y);
        af[2] = (short)f2bf(a0.z); af[3] = (short)f2bf(a0.w);
        af[4] = (short)f2bf(a1.x); af[5] = (short)f2bf(a1.y);
        af[6] = (short)f2bf(a1.z); af[7] = (short)f2bf(a1.w);
        const int kg = kh + kl;
        if (p < 2) {
          bf16x8 bhi = *(const bf16x8*)(&s.whhi[am][kg]);
          bf16x8 blo = *(const bf16x8*)(&s.whlo[am][kg]);
          accA = __builtin_amdgcn_mfma_f32_16x16x32_bf16(af, bhi, accA, 0, 0, 0);
          accB = __builtin_amdgcn_mfma_f32_16x16x32_bf16(af, blo, accB, 0, 0, 0);
        } else {
          bf16x8 bxx = *(const bf16x8*)(&s.wx[am][kg]);
          if (ss & 1) accB = __builtin_amdgcn_mfma_f32_16x16x32_bf16(af, bxx, accB, 0, 0, 0);
          else        accA = __builtin_amdgcn_mfma_f32_16x16x32_bf16(af, bxx, accA, 0, 0, 0);
        }
      }
    }

    // ---- cross-wave reduce + epilogue ----
    f32x4 acc = accA + accB;
    const int rbase = (aq << 6) + am;   // elem = row*16+col, row=aq*4+i, col=am
    s.red[wv][rbase     ] = acc[0];
    s.red[wv][rbase + 16] = acc[1];
    s.red[wv][rbase + 32] = acc[2];
    s.red[wv][rbase + 48] = acc[3];
    __syncthreads();
    float v = s.red[0][tid] + s.red[1][tid] + s.red[2][tid] + s.red[3][tid] + biasv;
    float h = tanhf(v);

    float* hwr = layer ? (hbuf2 + ((t + 1) & 1) * (BB * HH))
                       : (hbuf1 + (t + 1) * (BB * HH));
    hwr[off_bh] = h;
    if (layer) out[obase + t * HH] = h;                          // outputs [B,T,H]
    if (t == TT - 1) out[BB * TT * HH + layer * (BB * HH) + off_bh] = h;  // h_n [L,B,H]

    __threadfence();   // release: drain + make stores visible at agent scope
    __syncthreads();
    if (tid == 0)
      __hip_atomic_store(&flags[wg], (unsigned)(t + 1),
                         __ATOMIC_RELEASE, __HIP_MEMORY_SCOPE_AGENT);
  }
}

// Re-init per launch: harness re-poisons d_ws with 0xAA before every timed call.
__global__ void prep(float* hbuf1, float* hbuf2, unsigned* flags) {
  int i = blockIdx.x * 256 + threadIdx.x;
  if (i < BB * HH) { hbuf1[i] = 0.f; hbuf2[i] = 0.f; }  // h_{-1} = 0 slots
  if (i < 256) flags[i] = 0;
}

extern "C" void kernel_launch(void* const* d_in, const int* in_sizes, int n_in,
                              void* d_out, int out_size, void* d_ws, size_t ws_size,
                              hipStream_t stream) {
  const float* x  = (const float*)d_in[0];
  const float* Wx = (const float*)d_in[1];
  const float* Wh = (const float*)d_in[2];
  const float* bx = (const float*)d_in[3];
  const float* bh = (const float*)d_in[4];
  float* out = (float*)d_out;

  char* ws = (char*)d_ws;
  float* hbuf1 = (float*)ws;                               // (T+1)*B*H fp32 = 134.3 MB
  size_t off1  = (size_t)(TT + 1) * BB * HH * sizeof(float);
  float* hbuf2 = (float*)(ws + off1);                      // 2*B*H fp32 ping-pong
  size_t off2  = off1 + (size_t)2 * BB * HH * sizeof(float);
  unsigned* flags = (unsigned*)(ws + off2);                // 256 u32

  prep<<<128, 256, 0, stream>>>(hbuf1, hbuf2, flags);
  rnn_fused<<<256, 256, 0, stream>>>(x, Wx, Wh, bx, bh, out, hbuf1, hbuf2, flags);
}